// Round 11
// baseline (384.154 us; speedup 1.0000x reference)
//
#include <hip/hip_runtime.h>
#include <stdint.h>

typedef unsigned short u16;
typedef unsigned int u32;
typedef __bf16 bf16x8 __attribute__((ext_vector_type(8)));
typedef u16 u16x8 __attribute__((ext_vector_type(8)));
typedef float f32x4 __attribute__((ext_vector_type(4)));

#define LOG2E 1.44269504088896340736f

__device__ __forceinline__ u16 f2bf(float f) {
  u32 u = __float_as_uint(f);
  u += 0x7fffu + ((u >> 16) & 1u);   // RNE
  return (u16)(u >> 16);
}
__device__ __forceinline__ float bf2f(u16 s) { return __uint_as_float(((u32)s) << 16); }
__device__ __forceinline__ float fexp2(float x) { return __builtin_amdgcn_exp2f(x); }

struct alignas(8) U16x4 { u16 x, y, z, w; };

__device__ __forceinline__ void load_lds16(const u16* g, u16* l) {
  __builtin_amdgcn_global_load_lds((const __attribute__((address_space(1))) void*)g,
                                   (__attribute__((address_space(3))) void*)l, 16, 0, 0);
}

// ---------- fused: weight convert (fp32->bf16) + RMSNorm + t96f zeroing ----------
struct CvtArgs {
  const float* src[8];
  u16* dst[8];
  int cnt4[8];
  int total4;
};

__global__ __launch_bounds__(256) void prep_kernel(CvtArgs a,
                                                   const float* __restrict__ resid,
                                                   const float* __restrict__ w,
                                                   u16* __restrict__ xn,
                                                   float* __restrict__ t96f) {
  const int tid = threadIdx.x;
  if (blockIdx.x < 4096) {           // RMSNorm rows
    const int row = blockIdx.x;
    const float4 v = ((const float4*)(resid + (size_t)row * 1024))[tid];
    float ss = v.x * v.x + v.y * v.y + v.z * v.z + v.w * v.w;
#pragma unroll
    for (int off = 32; off > 0; off >>= 1) ss += __shfl_down(ss, off, 64);
    __shared__ float red[4];
    const int lane = tid & 63, wid = tid >> 6;
    if (lane == 0) red[wid] = ss;
    __syncthreads();
    const float tot = red[0] + red[1] + red[2] + red[3];
    const float sc = rsqrtf(tot * (1.0f / 1024.0f) + 1e-5f);
    const float4 wv = ((const float4*)w)[tid];
    U16x4 o;
    o.x = f2bf(v.x * sc * wv.x); o.y = f2bf(v.y * sc * wv.y);
    o.z = f2bf(v.z * sc * wv.z); o.w = f2bf(v.w * sc * wv.w);
    ((U16x4*)(xn + (size_t)row * 1024))[tid] = o;
  } else if (blockIdx.x < 4480) {    // zero t96f: 384 blocks x 256 x float4 = 393216 f
    const int g = (blockIdx.x - 4096) * 256 + tid;
    ((float4*)t96f)[g] = make_float4(0.f, 0.f, 0.f, 0.f);
  } else {                           // weight convert, grid-stride over 2048 blocks
    for (int g = (blockIdx.x - 4480) * 256 + tid; g < a.total4; g += 2048 * 256) {
      int i = 0, off = g;
      while (off >= a.cnt4[i]) { off -= a.cnt4[i]; ++i; }
      float4 v = make_float4(0.f, 0.f, 0.f, 0.f);
      if (a.src[i]) v = ((const float4*)a.src[i])[off];
      U16x4 o;
      o.x = f2bf(v.x); o.y = f2bf(v.y); o.z = f2bf(v.z); o.w = f2bf(v.w);
      ((U16x4*)a.dst[i])[off] = o;
    }
  }
}

__global__ __launch_bounds__(256) void cvt_t96_kernel(const float* __restrict__ src,
                                                      u16* __restrict__ dst) {
  const int g = blockIdx.x * 256 + threadIdx.x;
  const float4 v = ((const float4*)src)[g];
  U16x4 o;
  o.x = f2bf(v.x); o.y = f2bf(v.y); o.z = f2bf(v.z); o.w = f2bf(v.w);
  ((U16x4*)dst)[g] = o;
}

// ---------- bf16 MFMA GEMM: double-buffered, BK=64 (one barrier per K-step) ----------
// LDS rows are 128 B: bank group = chunk only, so swizzle chunk ^= (row&7), both sides.
// EPI: 0 = bf16 out col-split C1/C2; 1 = softplus(acc+bias) bf16; 2 = f32 out + resid add;
//      4 = f32 atomicAdd
template <int EPI>
__global__ __launch_bounds__(256) void gemm_bt(
    const u16* __restrict__ A, const u16* __restrict__ Bw,
    void* __restrict__ C1, void* __restrict__ C2,
    const float* __restrict__ bias, const float* __restrict__ resid,
    int Kslice, int lda, int ldb, int ldc, int split, int nstore) {
  __shared__ alignas(16) u16 As[2][128 * 64];
  __shared__ alignas(16) u16 Bs[2][128 * 64];
  const int tid = threadIdx.x;
  const int lane = tid & 63, wid = tid >> 6;
  const int wr = wid >> 1, wcid = wid & 1;

  int bx, by;
  {
    const int gy = gridDim.y;
    const int flat = blockIdx.y * 32 + blockIdx.x;
    if ((gy & 3) == 0) {
      const int xcd = flat & 7, idx = flat >> 3;
      const int sy = gy >> 2;
      bx = (xcd & 1) * 16 + (idx & 15);
      by = (xcd >> 1) * sy + (idx >> 4);
    } else { bx = blockIdx.x; by = blockIdx.y; }
  }

  const long brow = (long)bx * 128, bcol = (long)by * 128;
  const int kt0 = blockIdx.z * Kslice;
  const int nt = Kslice >> 6;

  f32x4 acc[4][4] = {};

  const int srow = tid >> 3;                        // 0..31 (4 issues cover 128 rows)
  const int scol = ((tid & 7) ^ (srow & 7)) * 8;    // pre-swizzled global 16B-chunk
  const u16* Ag = A + (brow + srow) * (long)lda + scol;
  const u16* Bg = Bw + (bcol + srow) * (long)ldb + scol;
  const int fr = lane & 15;
  const int fq = lane >> 4;
  const int ck0 = ((fq) ^ (fr & 7)) * 8;            // swizzled read chunk, kslice 0
  const int ck1 = ((4 + fq) ^ (fr & 7)) * 8;        // kslice 1

  auto stage = [&](int buf, int kt) {
    u16* Asp = As[buf] + tid * 8;
    u16* Bsp = Bs[buf] + tid * 8;
#pragma unroll
    for (int kq = 0; kq < 4; ++kq) {
      load_lds16(Ag + kt + (long)(kq * 32) * lda, Asp + kq * 2048);
      load_lds16(Bg + kt + (long)(kq * 32) * ldb, Bsp + kq * 2048);
    }
  };

  stage(0, kt0);
  __syncthreads();

  int cur = 0;
  for (int t = 0; t < nt; ++t) {
    if (t + 1 < nt) stage(cur ^ 1, kt0 + (t + 1) * 64);   // overlaps with compute below
#pragma unroll
    for (int ks = 0; ks < 2; ++ks) {
      const int ck = ks ? ck1 : ck0;
      bf16x8 af[4], bfr[4];
#pragma unroll
      for (int i = 0; i < 4; ++i) {
        af[i]  = *(const bf16x8*)(As[cur] + (wr * 64 + i * 16 + fr) * 64 + ck);
        bfr[i] = *(const bf16x8*)(Bs[cur] + (wcid * 64 + i * 16 + fr) * 64 + ck);
      }
#pragma unroll
      for (int i = 0; i < 4; ++i)
#pragma unroll
        for (int j = 0; j < 4; ++j)
          acc[i][j] = __builtin_amdgcn_mfma_f32_16x16x32_bf16(af[i], bfr[j], acc[i][j], 0, 0, 0);
    }
    if (t + 1 < nt) __syncthreads();  // drains vmcnt -> next buf staged; guards LDS reuse
    cur ^= 1;
  }

#pragma unroll
  for (int i = 0; i < 4; ++i) {
#pragma unroll
    for (int j = 0; j < 4; ++j) {
      const long col = bcol + wcid * 64 + j * 16 + fr;
      if ((int)col < nstore) {
#pragma unroll
        for (int r = 0; r < 4; ++r) {
          const long row = brow + wr * 64 + i * 16 + fq * 4 + r;
          float v = acc[i][j][r];
          if (EPI == 1) {
            v += bias[col];
            v = fmaxf(v, 0.f) + log1pf(__expf(-fabsf(v)));  // softplus
          }
          if (EPI == 4) {
            atomicAdd((float*)C1 + row * ldc + col, v);
          } else if (EPI == 2) {
            ((float*)C1)[row * ldc + col] = v + resid[row * ldc + col];
          } else if ((int)col < split) {
            ((u16*)C1)[row * ldc + col] = f2bf(v);
          } else {
            ((u16*)C2)[row * ldc + (col - split)] = f2bf(v);
          }
        }
      }
    }
  }
}

// ---------- causal depthwise conv (K=4) + SiLU, 8e/thread ----------
__global__ __launch_bounds__(256) void conv_silu_kernel(
    const u16* __restrict__ u, const float* __restrict__ cw, const float* __restrict__ cb,
    u16* __restrict__ xc) {
  const int row = blockIdx.x;          // b*2048 + l
  const int l = row & 2047;
  const int t = threadIdx.x;
  const int e0 = t * 8;
  const size_t base = (size_t)row * 2048 + e0;
  bf16x8 xv[4];
#pragma unroll
  for (int k = 0; k < 4; ++k) {
    const int ls = l - 3 + k;
    if (ls >= 0) xv[k] = *(const bf16x8*)(u + base + (long)(k - 3) * 2048);
    else { bf16x8 z = {}; xv[k] = z; }
  }
  u16x8 o;
#pragma unroll
  for (int j = 0; j < 8; ++j) {
    const int e = e0 + j;
    const float4 w = ((const float4*)cw)[e];
    float acc = cb[e];
    acc = fmaf(w.x, (float)xv[0][j], acc);
    acc = fmaf(w.y, (float)xv[1][j], acc);
    acc = fmaf(w.z, (float)xv[2][j], acc);
    acc = fmaf(w.w, (float)xv[3][j], acc);
    const float s = acc / (1.f + __expf(-acc));  // silu
    o[j] = f2bf(s);
  }
  *(u16x8*)(xc + base) = o;
}

// ---------- selective scan, chunked: 64 chunks x 32 steps ----------
__global__ __launch_bounds__(256) void scan_p1(
    const u16* __restrict__ delta, const u16* __restrict__ xc, const u16* __restrict__ t96,
    const float* __restrict__ A_log, float* __restrict__ P, float* __restrict__ H) {
  const int tid = threadIdx.x;
  const int e = blockIdx.x * 256 + tid;
  const int c = blockIdx.y, b = blockIdx.z;
  __shared__ alignas(16) u16 Dsh[32 * 256];
  __shared__ alignas(16) u16 Xsh[32 * 256];
  __shared__ float Bsh[32][16];
  const size_t rowbase = ((size_t)(b * 2048 + c * 32)) * 2048 + blockIdx.x * 256;
#pragma unroll
  for (int k = 0; k < 4; ++k) {
    const int i = tid + k * 256;
    const size_t go = rowbase + (size_t)(i >> 5) * 2048 + (i & 31) * 8;
    load_lds16(delta + go, Dsh + i * 8);
    load_lds16(xc + go, Xsh + i * 8);
  }
  for (int i = tid; i < 512; i += 256) {
    const int l0 = i >> 4, n = i & 15;
    Bsh[l0][n] = bf2f(t96[(size_t)(b * 2048 + c * 32 + l0) * 96 + 64 + n]);
  }
  float kv[16], h[16];
#pragma unroll
  for (int n = 0; n < 16; ++n) {
    kv[n] = -__expf(A_log[(size_t)e * 16 + n]) * LOG2E;
    h[n] = 0.f;
  }
  __syncthreads();
  float sdt = 0.f;
  for (int l0 = 0; l0 < 32; ++l0) {
    const float dt = bf2f(Dsh[l0 * 256 + tid]);
    const float x  = bf2f(Xsh[l0 * 256 + tid]);
    const float dtx = dt * x;
    sdt += dt;
#pragma unroll
    for (int n = 0; n < 16; ++n) {
      const float ab = fexp2(kv[n] * dt);
      h[n] = fmaf(ab, h[n], dtx * Bsh[l0][n]);
    }
  }
  const size_t o0 = (((size_t)(b * 64 + c)) * 16) * 2048 + e;
#pragma unroll
  for (int n = 0; n < 16; ++n) {
    P[o0 + (size_t)n * 2048] = fexp2(kv[n] * sdt);
    H[o0 + (size_t)n * 2048] = h[n];
  }
}

__global__ __launch_bounds__(256) void scan_p2(float* __restrict__ P, float* __restrict__ H) {
  const int g = blockIdx.x * 256 + threadIdx.x;  // 65536 = B*E*N
  const int e = g & 2047;
  const int n = (g >> 11) & 15;
  const int b = g >> 15;
  const size_t base = (((size_t)(b * 64)) * 16 + n) * 2048 + e;
  float h = 0.f;
  for (int c = 0; c < 64; ++c) {
    const size_t a = base + (size_t)c * (16 * 2048);
    const float Pc = P[a], hl = H[a];
    H[a] = h;
    h = fmaf(Pc, h, hl);
  }
}

__global__ __launch_bounds__(256) void scan_p3(
    const u16* __restrict__ delta, const u16* __restrict__ xc, const u16* __restrict__ t96,
    const float* __restrict__ A_log, const float* __restrict__ Hin,
    const u16* __restrict__ skip, const float* __restrict__ W_D, u16* __restrict__ ybar) {
  const int tid = threadIdx.x;
  const int e = blockIdx.x * 256 + tid;
  const int c = blockIdx.y, b = blockIdx.z;
  __shared__ alignas(16) u16 Dsh[32 * 256];
  __shared__ alignas(16) u16 Xsh[32 * 256];
  __shared__ float Bsh[32][16], Csh[32][16];
  const size_t rowbase = ((size_t)(b * 2048 + c * 32)) * 2048 + blockIdx.x * 256;
#pragma unroll
  for (int k = 0; k < 4; ++k) {
    const int i = tid + k * 256;
    const size_t go = rowbase + (size_t)(i >> 5) * 2048 + (i & 31) * 8;
    load_lds16(delta + go, Dsh + i * 8);
    load_lds16(xc + go, Xsh + i * 8);
  }
  for (int i = tid; i < 512; i += 256) {
    const int l0 = i >> 4, n = i & 15;
    const size_t rowo = (size_t)(b * 2048 + c * 32 + l0) * 96;
    Bsh[l0][n] = bf2f(t96[rowo + 64 + n]);
    Csh[l0][n] = bf2f(t96[rowo + 80 + n]);
  }
  float kv[16], h[16];
  const size_t o0 = (((size_t)(b * 64 + c)) * 16) * 2048 + e;
#pragma unroll
  for (int n = 0; n < 16; ++n) {
    kv[n] = -__expf(A_log[(size_t)e * 16 + n]) * LOG2E;
    h[n] = Hin[o0 + (size_t)n * 2048];
  }
  const float wd = W_D[e];
  __syncthreads();
  const size_t base = ((size_t)(b * 2048 + c * 32)) * 2048 + e;
  for (int l0 = 0; l0 < 32; ++l0) {
    const float dt = bf2f(Dsh[l0 * 256 + tid]);
    const float x  = bf2f(Xsh[l0 * 256 + tid]);
    const float dtx = dt * x;
    float y = 0.f;
#pragma unroll
    for (int n = 0; n < 16; ++n) {
      const float ab = fexp2(kv[n] * dt);
      h[n] = fmaf(ab, h[n], dtx * Bsh[l0][n]);
      y = fmaf(h[n], Csh[l0][n], y);
    }
    y = fmaf(x, wd, y);
    const float s = bf2f(skip[base + (size_t)l0 * 2048]);
    y *= s / (1.f + __expf(-s));
    ybar[base + (size_t)l0 * 2048] = f2bf(y);
  }
}

// ---------- launch ----------
extern "C" void kernel_launch(void* const* d_in, const int* in_sizes, int n_in,
                              void* d_out, int out_size, void* d_ws, size_t ws_size,
                              hipStream_t stream) {
  const float* resid  = (const float*)d_in[0];
  const float* norm_w = (const float*)d_in[1];
  const float* skip_w = (const float*)d_in[2];
  const float* in_w   = (const float*)d_in[3];
  const float* conv_w = (const float*)d_in[4];
  const float* conv_b = (const float*)d_in[5];
  const float* wd1    = (const float*)d_in[6];
  const float* wd2    = (const float*)d_in[7];
  const float* wd2_b  = (const float*)d_in[8];
  const float* wb     = (const float*)d_in[9];
  const float* wc     = (const float*)d_in[10];
  const float* A_log  = (const float*)d_in[11];
  const float* W_D    = (const float*)d_in[12];
  const float* out_w  = (const float*)d_in[13];
  float* out = (float*)d_out;

  char* ws = (char*)d_ws;
  u16* w_in   = (u16*)(ws + 0);          // w_in|w_skip contiguous = fused 4096x1024 weight
  u16* w_skip = (u16*)(ws + 4194304);
  u16* w_out  = (u16*)(ws + 8388608);
  u16* w_wd2  = (u16*)(ws + 12582912);
  u16* w2cat  = (u16*)(ws + 12845056);   // 128 x 2048 (wd1,wb,wc,zeros)
  u16* xn     = (u16*)(ws + 13369344);   // 4096 x 1024
  u16* u      = (u16*)(ws + 21757952);   // 4096 x 2048
  u16* delta  = u;                       // alias: u dead after conv
  u16* skip   = (u16*)(ws + 38535168);   // 4096 x 2048
  u16* xc     = (u16*)(ws + 55312384);   // 4096 x 2048
  u16* t96    = (u16*)(ws + 72089600);   // 4096 x 96 bf16
  float* P    = (float*)(ws + 72876032); // (B,64,16,E)
  float* t96f = (float*)(ws + 72876032); // alias: split-K f32 accum (dead before P live)
  u16* ybar   = (u16*)(ws + 72876032);   // alias: P dead after phase 2
  float* H    = (float*)(ws + 89653248); // (B,64,16,E)

  CvtArgs ca{};
  ca.src[0] = in_w;   ca.dst[0] = w_in;              ca.cnt4[0] = 2097152 / 4;
  ca.src[1] = skip_w; ca.dst[1] = w_skip;            ca.cnt4[1] = 2097152 / 4;
  ca.src[2] = out_w;  ca.dst[2] = w_out;             ca.cnt4[2] = 2097152 / 4;
  ca.src[3] = wd2;    ca.dst[3] = w_wd2;             ca.cnt4[3] = 131072 / 4;
  ca.src[4] = wd1;    ca.dst[4] = w2cat;             ca.cnt4[4] = 131072 / 4;
  ca.src[5] = wb;     ca.dst[5] = w2cat + 64 * 2048; ca.cnt4[5] = 32768 / 4;
  ca.src[6] = wc;     ca.dst[6] = w2cat + 80 * 2048; ca.cnt4[6] = 32768 / 4;
  ca.src[7] = nullptr;ca.dst[7] = w2cat + 96 * 2048; ca.cnt4[7] = 65536 / 4;
  ca.total4 = (2097152 * 3 + 131072 * 2 + 32768 * 2 + 65536) / 4;

  // fused weight-convert + RMSNorm + t96f zeroing (one launch)
  prep_kernel<<<6528, 256, 0, stream>>>(ca, resid, norm_w, xn, t96f);

  // fused: [u | skip] = xn @ [in_w; skip_w]^T   (M=4096, N=4096, K=1024)
  gemm_bt<0><<<dim3(32, 32), 256, 0, stream>>>(xn, w_in, u, skip, nullptr, nullptr,
                                               1024, 1024, 1024, 2048, 2048, 4096);

  conv_silu_kernel<<<4096, 256, 0, stream>>>(u, conv_w, conv_b, xc);

  // t96f = xc @ [wd1;wb;wc]^T, split-K x8 with f32 atomics (256 blocks)
  gemm_bt<4><<<dim3(32, 1, 8), 256, 0, stream>>>(xc, w2cat, t96f, nullptr, nullptr, nullptr,
                                                 256, 2048, 2048, 96, 1 << 30, 96);
  cvt_t96_kernel<<<384, 256, 0, stream>>>(t96f, t96);

  // delta = softplus(dtr @ wd2^T + b)   (K=64 -> nt=1, single-buffer path)
  gemm_bt<1><<<dim3(32, 16), 256, 0, stream>>>(t96, w_wd2, delta, nullptr, wd2_b, nullptr,
                                               64, 96, 64, 2048, 1 << 30, 2048);

  scan_p1<<<dim3(8, 64, 2), 256, 0, stream>>>(delta, xc, t96, A_log, P, H);
  scan_p2<<<256, 256, 0, stream>>>(P, H);
  scan_p3<<<dim3(8, 64, 2), 256, 0, stream>>>(delta, xc, t96, A_log, H, skip, W_D, ybar);

  // out = resid + ybar @ out_w^T : init out with resid (D2D), split-K x2 atomics
  hipMemcpyAsync(out, resid, 4096 * 1024 * 4, hipMemcpyDeviceToDevice, stream);
  gemm_bt<4><<<dim3(32, 8, 2), 256, 0, stream>>>(ybar, w_out, out, nullptr, nullptr, nullptr,
                                                 1024, 2048, 2048, 1024, 1 << 30, 1024);
}

// Round 12
// 321.709 us; speedup vs baseline: 1.1941x; 1.1941x over previous
//
#include <hip/hip_runtime.h>
#include <stdint.h>

typedef unsigned short u16;
typedef unsigned int u32;
typedef __bf16 bf16x8 __attribute__((ext_vector_type(8)));
typedef u16 u16x8 __attribute__((ext_vector_type(8)));
typedef float f32x4 __attribute__((ext_vector_type(4)));

#define LOG2E 1.44269504088896340736f

__device__ __forceinline__ u16 f2bf(float f) {
  u32 u = __float_as_uint(f);
  u += 0x7fffu + ((u >> 16) & 1u);   // RNE
  return (u16)(u >> 16);
}
__device__ __forceinline__ float bf2f(u16 s) { return __uint_as_float(((u32)s) << 16); }
__device__ __forceinline__ float fexp2(float x) { return __builtin_amdgcn_exp2f(x); }

struct alignas(8) U16x4 { u16 x, y, z, w; };

__device__ __forceinline__ void load_lds16(const u16* g, u16* l) {
  __builtin_amdgcn_global_load_lds((const __attribute__((address_space(1))) void*)g,
                                   (__attribute__((address_space(3))) void*)l, 16, 0, 0);
}

// ---------- fused: weight convert (fp32->bf16) + RMSNorm ----------
struct CvtArgs {
  const float* src[8];
  u16* dst[8];
  int cnt4[8];
  int total4;
};

__global__ __launch_bounds__(256) void prep_kernel(CvtArgs a,
                                                   const float* __restrict__ resid,
                                                   const float* __restrict__ w,
                                                   u16* __restrict__ xn) {
  const int tid = threadIdx.x;
  if (blockIdx.x < 4096) {           // RMSNorm rows
    const int row = blockIdx.x;
    const float4 v = ((const float4*)(resid + (size_t)row * 1024))[tid];
    float ss = v.x * v.x + v.y * v.y + v.z * v.z + v.w * v.w;
#pragma unroll
    for (int off = 32; off > 0; off >>= 1) ss += __shfl_down(ss, off, 64);
    __shared__ float red[4];
    const int lane = tid & 63, wid = tid >> 6;
    if (lane == 0) red[wid] = ss;
    __syncthreads();
    const float tot = red[0] + red[1] + red[2] + red[3];
    const float sc = rsqrtf(tot * (1.0f / 1024.0f) + 1e-5f);
    const float4 wv = ((const float4*)w)[tid];
    U16x4 o;
    o.x = f2bf(v.x * sc * wv.x); o.y = f2bf(v.y * sc * wv.y);
    o.z = f2bf(v.z * sc * wv.z); o.w = f2bf(v.w * sc * wv.w);
    ((U16x4*)(xn + (size_t)row * 1024))[tid] = o;
  } else {                           // weight convert, grid-stride over 2048 blocks
    for (int g = (blockIdx.x - 4096) * 256 + tid; g < a.total4; g += 2048 * 256) {
      int i = 0, off = g;
      while (off >= a.cnt4[i]) { off -= a.cnt4[i]; ++i; }
      float4 v = make_float4(0.f, 0.f, 0.f, 0.f);
      if (a.src[i]) v = ((const float4*)a.src[i])[off];
      U16x4 o;
      o.x = f2bf(v.x); o.y = f2bf(v.y); o.z = f2bf(v.z); o.w = f2bf(v.w);
      ((U16x4*)a.dst[i])[off] = o;
    }
  }
}

// ---------- reduce 4 split-K partials (f32) -> t96 bf16 ----------
__global__ __launch_bounds__(256) void reduce_t96_kernel(const float* __restrict__ p,
                                                         u16* __restrict__ dst) {
  const int g = blockIdx.x * 256 + threadIdx.x;   // 98304 float4s
  const int S = 4096 * 96 / 4;                     // partial stride in float4
  float4 v0 = ((const float4*)p)[g];
  float4 v1 = ((const float4*)p)[g + S];
  float4 v2 = ((const float4*)p)[g + 2 * S];
  float4 v3 = ((const float4*)p)[g + 3 * S];
  U16x4 o;
  o.x = f2bf(v0.x + v1.x + v2.x + v3.x);
  o.y = f2bf(v0.y + v1.y + v2.y + v3.y);
  o.z = f2bf(v0.z + v1.z + v2.z + v3.z);
  o.w = f2bf(v0.w + v1.w + v2.w + v3.w);
  ((U16x4*)dst)[g] = o;
}

// ---------- bf16 MFMA GEMM: double-buffered, BK=64 (one barrier per K-step) ----------
// LDS rows are 128 B: bank group = chunk only, so swizzle chunk ^= (row&7), both sides.
// EPI: 0 = bf16 out col-split C1/C2; 1 = softplus(acc+bias) bf16; 2 = f32 out + resid add;
//      5 = f32 partial store at C1 + blockIdx.z*split (coalesced, no atomics)
template <int EPI>
__global__ __launch_bounds__(256) void gemm_bt(
    const u16* __restrict__ A, const u16* __restrict__ Bw,
    void* __restrict__ C1, void* __restrict__ C2,
    const float* __restrict__ bias, const float* __restrict__ resid,
    int Kslice, int lda, int ldb, int ldc, int split, int nstore) {
  __shared__ alignas(16) u16 As[2][128 * 64];
  __shared__ alignas(16) u16 Bs[2][128 * 64];
  const int tid = threadIdx.x;
  const int lane = tid & 63, wid = tid >> 6;
  const int wr = wid >> 1, wcid = wid & 1;

  int bx, by;
  {
    const int gy = gridDim.y;
    const int flat = blockIdx.y * 32 + blockIdx.x;
    if ((gy & 3) == 0) {
      const int xcd = flat & 7, idx = flat >> 3;
      const int sy = gy >> 2;
      bx = (xcd & 1) * 16 + (idx & 15);
      by = (xcd >> 1) * sy + (idx >> 4);
    } else { bx = blockIdx.x; by = blockIdx.y; }
  }

  const long brow = (long)bx * 128, bcol = (long)by * 128;
  const int kt0 = blockIdx.z * Kslice;
  const int nt = Kslice >> 6;

  f32x4 acc[4][4] = {};

  const int srow = tid >> 3;                        // 0..31 (4 issues cover 128 rows)
  const int scol = ((tid & 7) ^ (srow & 7)) * 8;    // pre-swizzled global 16B-chunk
  const u16* Ag = A + (brow + srow) * (long)lda + scol;
  const u16* Bg = Bw + (bcol + srow) * (long)ldb + scol;
  const int fr = lane & 15;
  const int fq = lane >> 4;
  const int ck0 = ((fq) ^ (fr & 7)) * 8;            // swizzled read chunk, kslice 0
  const int ck1 = ((4 + fq) ^ (fr & 7)) * 8;        // kslice 1

  auto stage = [&](int buf, int kt) {
    u16* Asp = As[buf] + tid * 8;
    u16* Bsp = Bs[buf] + tid * 8;
#pragma unroll
    for (int kq = 0; kq < 4; ++kq) {
      load_lds16(Ag + kt + (long)(kq * 32) * lda, Asp + kq * 2048);
      load_lds16(Bg + kt + (long)(kq * 32) * ldb, Bsp + kq * 2048);
    }
  };

  stage(0, kt0);
  __syncthreads();

  int cur = 0;
  for (int t = 0; t < nt; ++t) {
    if (t + 1 < nt) stage(cur ^ 1, kt0 + (t + 1) * 64);   // overlaps with compute below
#pragma unroll
    for (int ks = 0; ks < 2; ++ks) {
      const int ck = ks ? ck1 : ck0;
      bf16x8 af[4], bfr[4];
#pragma unroll
      for (int i = 0; i < 4; ++i) {
        af[i]  = *(const bf16x8*)(As[cur] + (wr * 64 + i * 16 + fr) * 64 + ck);
        bfr[i] = *(const bf16x8*)(Bs[cur] + (wcid * 64 + i * 16 + fr) * 64 + ck);
      }
#pragma unroll
      for (int i = 0; i < 4; ++i)
#pragma unroll
        for (int j = 0; j < 4; ++j)
          acc[i][j] = __builtin_amdgcn_mfma_f32_16x16x32_bf16(af[i], bfr[j], acc[i][j], 0, 0, 0);
    }
    if (t + 1 < nt) __syncthreads();  // drains vmcnt -> next buf staged; guards LDS reuse
    cur ^= 1;
  }

#pragma unroll
  for (int i = 0; i < 4; ++i) {
#pragma unroll
    for (int j = 0; j < 4; ++j) {
      const long col = bcol + wcid * 64 + j * 16 + fr;
      if ((int)col < nstore) {
#pragma unroll
        for (int r = 0; r < 4; ++r) {
          const long row = brow + wr * 64 + i * 16 + fq * 4 + r;
          float v = acc[i][j][r];
          if (EPI == 1) {
            v += bias[col];
            v = fmaxf(v, 0.f) + log1pf(__expf(-fabsf(v)));  // softplus
          }
          if (EPI == 5) {
            ((float*)C1)[(size_t)blockIdx.z * split + row * ldc + col] = v;
          } else if (EPI == 2) {
            ((float*)C1)[row * ldc + col] = v + resid[row * ldc + col];
          } else if (EPI == 0 && (int)col < split) {
            ((u16*)C1)[row * ldc + col] = f2bf(v);
          } else if (EPI == 0) {
            ((u16*)C2)[row * ldc + (col - split)] = f2bf(v);
          } else if (EPI == 1) {
            ((u16*)C1)[row * ldc + col] = f2bf(v);
          }
        }
      }
    }
  }
}

// ---------- causal depthwise conv (K=4) + SiLU, 8e/thread ----------
__global__ __launch_bounds__(256) void conv_silu_kernel(
    const u16* __restrict__ u, const float* __restrict__ cw, const float* __restrict__ cb,
    u16* __restrict__ xc) {
  const int row = blockIdx.x;          // b*2048 + l
  const int l = row & 2047;
  const int t = threadIdx.x;
  const int e0 = t * 8;
  const size_t base = (size_t)row * 2048 + e0;
  bf16x8 xv[4];
#pragma unroll
  for (int k = 0; k < 4; ++k) {
    const int ls = l - 3 + k;
    if (ls >= 0) xv[k] = *(const bf16x8*)(u + base + (long)(k - 3) * 2048);
    else { bf16x8 z = {}; xv[k] = z; }
  }
  u16x8 o;
#pragma unroll
  for (int j = 0; j < 8; ++j) {
    const int e = e0 + j;
    const float4 w = ((const float4*)cw)[e];
    float acc = cb[e];
    acc = fmaf(w.x, (float)xv[0][j], acc);
    acc = fmaf(w.y, (float)xv[1][j], acc);
    acc = fmaf(w.z, (float)xv[2][j], acc);
    acc = fmaf(w.w, (float)xv[3][j], acc);
    const float s = acc / (1.f + __expf(-acc));  // silu
    o[j] = f2bf(s);
  }
  *(u16x8*)(xc + base) = o;
}

// ---------- selective scan, chunked: 64 chunks x 32 steps ----------
__global__ __launch_bounds__(256) void scan_p1(
    const u16* __restrict__ delta, const u16* __restrict__ xc, const u16* __restrict__ t96,
    const float* __restrict__ A_log, float* __restrict__ P, float* __restrict__ H) {
  const int tid = threadIdx.x;
  const int e = blockIdx.x * 256 + tid;
  const int c = blockIdx.y, b = blockIdx.z;
  __shared__ alignas(16) u16 Dsh[32 * 256];
  __shared__ alignas(16) u16 Xsh[32 * 256];
  __shared__ float Bsh[32][16];
  const size_t rowbase = ((size_t)(b * 2048 + c * 32)) * 2048 + blockIdx.x * 256;
#pragma unroll
  for (int k = 0; k < 4; ++k) {
    const int i = tid + k * 256;
    const size_t go = rowbase + (size_t)(i >> 5) * 2048 + (i & 31) * 8;
    load_lds16(delta + go, Dsh + i * 8);
    load_lds16(xc + go, Xsh + i * 8);
  }
  for (int i = tid; i < 512; i += 256) {
    const int l0 = i >> 4, n = i & 15;
    Bsh[l0][n] = bf2f(t96[(size_t)(b * 2048 + c * 32 + l0) * 96 + 64 + n]);
  }
  float kv[16], h[16];
#pragma unroll
  for (int n = 0; n < 16; ++n) {
    kv[n] = -__expf(A_log[(size_t)e * 16 + n]) * LOG2E;
    h[n] = 0.f;
  }
  __syncthreads();
  float sdt = 0.f;
  for (int l0 = 0; l0 < 32; ++l0) {
    const float dt = bf2f(Dsh[l0 * 256 + tid]);
    const float x  = bf2f(Xsh[l0 * 256 + tid]);
    const float dtx = dt * x;
    sdt += dt;
#pragma unroll
    for (int n = 0; n < 16; ++n) {
      const float ab = fexp2(kv[n] * dt);
      h[n] = fmaf(ab, h[n], dtx * Bsh[l0][n]);
    }
  }
  const size_t o0 = (((size_t)(b * 64 + c)) * 16) * 2048 + e;
#pragma unroll
  for (int n = 0; n < 16; ++n) {
    P[o0 + (size_t)n * 2048] = fexp2(kv[n] * sdt);
    H[o0 + (size_t)n * 2048] = h[n];
  }
}

__global__ __launch_bounds__(256) void scan_p2(float* __restrict__ P, float* __restrict__ H) {
  const int g = blockIdx.x * 256 + threadIdx.x;  // 65536 = B*E*N
  const int e = g & 2047;
  const int n = (g >> 11) & 15;
  const int b = g >> 15;
  const size_t base = (((size_t)(b * 64)) * 16 + n) * 2048 + e;
  float h = 0.f;
  for (int c = 0; c < 64; ++c) {
    const size_t a = base + (size_t)c * (16 * 2048);
    const float Pc = P[a], hl = H[a];
    H[a] = h;
    h = fmaf(Pc, h, hl);
  }
}

__global__ __launch_bounds__(256) void scan_p3(
    const u16* __restrict__ delta, const u16* __restrict__ xc, const u16* __restrict__ t96,
    const float* __restrict__ A_log, const float* __restrict__ Hin,
    const u16* __restrict__ skip, const float* __restrict__ W_D, u16* __restrict__ ybar) {
  const int tid = threadIdx.x;
  const int e = blockIdx.x * 256 + tid;
  const int c = blockIdx.y, b = blockIdx.z;
  __shared__ alignas(16) u16 Dsh[32 * 256];
  __shared__ alignas(16) u16 Xsh[32 * 256];
  __shared__ float Bsh[32][16], Csh[32][16];
  const size_t rowbase = ((size_t)(b * 2048 + c * 32)) * 2048 + blockIdx.x * 256;
#pragma unroll
  for (int k = 0; k < 4; ++k) {
    const int i = tid + k * 256;
    const size_t go = rowbase + (size_t)(i >> 5) * 2048 + (i & 31) * 8;
    load_lds16(delta + go, Dsh + i * 8);
    load_lds16(xc + go, Xsh + i * 8);
  }
  for (int i = tid; i < 512; i += 256) {
    const int l0 = i >> 4, n = i & 15;
    const size_t rowo = (size_t)(b * 2048 + c * 32 + l0) * 96;
    Bsh[l0][n] = bf2f(t96[rowo + 64 + n]);
    Csh[l0][n] = bf2f(t96[rowo + 80 + n]);
  }
  float kv[16], h[16];
  const size_t o0 = (((size_t)(b * 64 + c)) * 16) * 2048 + e;
#pragma unroll
  for (int n = 0; n < 16; ++n) {
    kv[n] = -__expf(A_log[(size_t)e * 16 + n]) * LOG2E;
    h[n] = Hin[o0 + (size_t)n * 2048];
  }
  const float wd = W_D[e];
  __syncthreads();
  const size_t base = ((size_t)(b * 2048 + c * 32)) * 2048 + e;
  for (int l0 = 0; l0 < 32; ++l0) {
    const float dt = bf2f(Dsh[l0 * 256 + tid]);
    const float x  = bf2f(Xsh[l0 * 256 + tid]);
    const float dtx = dt * x;
    float y = 0.f;
#pragma unroll
    for (int n = 0; n < 16; ++n) {
      const float ab = fexp2(kv[n] * dt);
      h[n] = fmaf(ab, h[n], dtx * Bsh[l0][n]);
      y = fmaf(h[n], Csh[l0][n], y);
    }
    y = fmaf(x, wd, y);
    const float s = bf2f(skip[base + (size_t)l0 * 2048]);
    y *= s / (1.f + __expf(-s));
    ybar[base + (size_t)l0 * 2048] = f2bf(y);
  }
}

// ---------- launch ----------
extern "C" void kernel_launch(void* const* d_in, const int* in_sizes, int n_in,
                              void* d_out, int out_size, void* d_ws, size_t ws_size,
                              hipStream_t stream) {
  const float* resid  = (const float*)d_in[0];
  const float* norm_w = (const float*)d_in[1];
  const float* skip_w = (const float*)d_in[2];
  const float* in_w   = (const float*)d_in[3];
  const float* conv_w = (const float*)d_in[4];
  const float* conv_b = (const float*)d_in[5];
  const float* wd1    = (const float*)d_in[6];
  const float* wd2    = (const float*)d_in[7];
  const float* wd2_b  = (const float*)d_in[8];
  const float* wb     = (const float*)d_in[9];
  const float* wc     = (const float*)d_in[10];
  const float* A_log  = (const float*)d_in[11];
  const float* W_D    = (const float*)d_in[12];
  const float* out_w  = (const float*)d_in[13];
  float* out = (float*)d_out;

  char* ws = (char*)d_ws;
  u16* w_in   = (u16*)(ws + 0);          // w_in|w_skip contiguous = fused 4096x1024 weight
  u16* w_skip = (u16*)(ws + 4194304);
  u16* w_out  = (u16*)(ws + 8388608);
  u16* w_wd2  = (u16*)(ws + 12582912);
  u16* w2cat  = (u16*)(ws + 12845056);   // 128 x 2048 (wd1,wb,wc,zeros)
  u16* xn     = (u16*)(ws + 13369344);   // 4096 x 1024
  u16* u      = (u16*)(ws + 21757952);   // 4096 x 2048
  u16* delta  = u;                       // alias: u dead after conv
  u16* skip   = (u16*)(ws + 38535168);   // 4096 x 2048
  u16* xc     = (u16*)(ws + 55312384);   // 4096 x 2048
  u16* t96    = (u16*)(ws + 72089600);   // 4096 x 96 bf16
  float* P    = (float*)(ws + 72876032); // (B,64,16,E)
  float* t96f = (float*)(ws + 72876032); // alias: 4 x (4096x96) f32 partials (dead before P)
  u16* ybar   = (u16*)(ws + 72876032);   // alias: P dead after phase 2
  float* H    = (float*)(ws + 89653248); // (B,64,16,E)

  CvtArgs ca{};
  ca.src[0] = in_w;   ca.dst[0] = w_in;              ca.cnt4[0] = 2097152 / 4;
  ca.src[1] = skip_w; ca.dst[1] = w_skip;            ca.cnt4[1] = 2097152 / 4;
  ca.src[2] = out_w;  ca.dst[2] = w_out;             ca.cnt4[2] = 2097152 / 4;
  ca.src[3] = wd2;    ca.dst[3] = w_wd2;             ca.cnt4[3] = 131072 / 4;
  ca.src[4] = wd1;    ca.dst[4] = w2cat;             ca.cnt4[4] = 131072 / 4;
  ca.src[5] = wb;     ca.dst[5] = w2cat + 64 * 2048; ca.cnt4[5] = 32768 / 4;
  ca.src[6] = wc;     ca.dst[6] = w2cat + 80 * 2048; ca.cnt4[6] = 32768 / 4;
  ca.src[7] = nullptr;ca.dst[7] = w2cat + 96 * 2048; ca.cnt4[7] = 65536 / 4;
  ca.total4 = (2097152 * 3 + 131072 * 2 + 32768 * 2 + 65536) / 4;

  // fused weight-convert + RMSNorm (one launch)
  prep_kernel<<<6144, 256, 0, stream>>>(ca, resid, norm_w, xn);

  // fused: [u | skip] = xn @ [in_w; skip_w]^T   (M=4096, N=4096, K=1024)
  gemm_bt<0><<<dim3(32, 32), 256, 0, stream>>>(xn, w_in, u, skip, nullptr, nullptr,
                                               1024, 1024, 1024, 2048, 2048, 4096);

  conv_silu_kernel<<<4096, 256, 0, stream>>>(u, conv_w, conv_b, xc);

  // t96 partials = xc @ [wd1;wb;wc]^T, split-K x4, coalesced f32 stores (no atomics)
  gemm_bt<5><<<dim3(32, 1, 4), 256, 0, stream>>>(xc, w2cat, t96f, nullptr, nullptr, nullptr,
                                                 512, 2048, 2048, 96, 4096 * 96, 96);
  reduce_t96_kernel<<<384, 256, 0, stream>>>(t96f, t96);

  // delta = softplus(dtr @ wd2^T + b)   (K=64 -> nt=1, single-buffer path)
  gemm_bt<1><<<dim3(32, 16), 256, 0, stream>>>(t96, w_wd2, delta, nullptr, wd2_b, nullptr,
                                               64, 96, 64, 2048, 1 << 30, 2048);

  scan_p1<<<dim3(8, 64, 2), 256, 0, stream>>>(delta, xc, t96, A_log, P, H);
  scan_p2<<<256, 256, 0, stream>>>(P, H);
  scan_p3<<<dim3(8, 64, 2), 256, 0, stream>>>(delta, xc, t96, A_log, H, skip, W_D, ybar);

  // out = resid + ybar @ out_w^T : single GEMM, fused resid-add epilogue (proven 43.8us)
  gemm_bt<2><<<dim3(32, 8), 256, 0, stream>>>(ybar, w_out, out, nullptr, nullptr, resid,
                                              2048, 2048, 2048, 1024, 1 << 30, 1024);
}

// Round 13
// 309.769 us; speedup vs baseline: 1.2401x; 1.0385x over previous
//
#include <hip/hip_runtime.h>
#include <stdint.h>

typedef unsigned short u16;
typedef unsigned int u32;
typedef __bf16 bf16x8 __attribute__((ext_vector_type(8)));
typedef u16 u16x8 __attribute__((ext_vector_type(8)));
typedef float f32x4 __attribute__((ext_vector_type(4)));

#define LOG2E 1.44269504088896340736f

__device__ __forceinline__ u16 f2bf(float f) {
  u32 u = __float_as_uint(f);
  u += 0x7fffu + ((u >> 16) & 1u);   // RNE
  return (u16)(u >> 16);
}
__device__ __forceinline__ float bf2f(u16 s) { return __uint_as_float(((u32)s) << 16); }
__device__ __forceinline__ float fexp2(float x) { return __builtin_amdgcn_exp2f(x); }

struct alignas(8) U16x4 { u16 x, y, z, w; };

__device__ __forceinline__ void load_lds16(const u16* g, u16* l) {
  __builtin_amdgcn_global_load_lds((const __attribute__((address_space(1))) void*)g,
                                   (__attribute__((address_space(3))) void*)l, 16, 0, 0);
}

// ---------- fused: weight convert (fp32->bf16) + RMSNorm ----------
struct CvtArgs {
  const float* src[8];
  u16* dst[8];
  int cnt4[8];
  int total4;
};

__global__ __launch_bounds__(256) void prep_kernel(CvtArgs a,
                                                   const float* __restrict__ resid,
                                                   const float* __restrict__ w,
                                                   u16* __restrict__ xn) {
  const int tid = threadIdx.x;
  if (blockIdx.x < 4096) {           // RMSNorm rows
    const int row = blockIdx.x;
    const float4 v = ((const float4*)(resid + (size_t)row * 1024))[tid];
    float ss = v.x * v.x + v.y * v.y + v.z * v.z + v.w * v.w;
#pragma unroll
    for (int off = 32; off > 0; off >>= 1) ss += __shfl_down(ss, off, 64);
    __shared__ float red[4];
    const int lane = tid & 63, wid = tid >> 6;
    if (lane == 0) red[wid] = ss;
    __syncthreads();
    const float tot = red[0] + red[1] + red[2] + red[3];
    const float sc = rsqrtf(tot * (1.0f / 1024.0f) + 1e-5f);
    const float4 wv = ((const float4*)w)[tid];
    U16x4 o;
    o.x = f2bf(v.x * sc * wv.x); o.y = f2bf(v.y * sc * wv.y);
    o.z = f2bf(v.z * sc * wv.z); o.w = f2bf(v.w * sc * wv.w);
    ((U16x4*)(xn + (size_t)row * 1024))[tid] = o;
  } else {                           // weight convert, grid-stride over 2048 blocks
    for (int g = (blockIdx.x - 4096) * 256 + tid; g < a.total4; g += 2048 * 256) {
      int i = 0, off = g;
      while (off >= a.cnt4[i]) { off -= a.cnt4[i]; ++i; }
      float4 v = make_float4(0.f, 0.f, 0.f, 0.f);
      if (a.src[i]) v = ((const float4*)a.src[i])[off];
      U16x4 o;
      o.x = f2bf(v.x); o.y = f2bf(v.y); o.z = f2bf(v.z); o.w = f2bf(v.w);
      ((U16x4*)a.dst[i])[off] = o;
    }
  }
}

// ---------- reduce 4 split-K partials (f32) -> t96 bf16 ----------
__global__ __launch_bounds__(256) void reduce_t96_kernel(const float* __restrict__ p,
                                                         u16* __restrict__ dst) {
  const int g = blockIdx.x * 256 + threadIdx.x;   // 98304 float4s
  const int S = 4096 * 96 / 4;                     // partial stride in float4
  float4 v0 = ((const float4*)p)[g];
  float4 v1 = ((const float4*)p)[g + S];
  float4 v2 = ((const float4*)p)[g + 2 * S];
  float4 v3 = ((const float4*)p)[g + 3 * S];
  U16x4 o;
  o.x = f2bf(v0.x + v1.x + v2.x + v3.x);
  o.y = f2bf(v0.y + v1.y + v2.y + v3.y);
  o.z = f2bf(v0.z + v1.z + v2.z + v3.z);
  o.w = f2bf(v0.w + v1.w + v2.w + v3.w);
  ((U16x4*)dst)[g] = o;
}

// ---------- out = resid + p0 + p1 (out-proj split-K reduce, fused resid add) ----------
__global__ __launch_bounds__(256) void reduce_out_kernel(const float* __restrict__ p,
                                                         const float* __restrict__ resid,
                                                         float* __restrict__ out) {
  const int g = blockIdx.x * 256 + threadIdx.x;   // 1048576 float4s
  const int S = 4096 * 1024 / 4;                   // partial stride in float4
  const float4 a = ((const float4*)p)[g];
  const float4 b = ((const float4*)p)[g + S];
  const float4 r = ((const float4*)resid)[g];
  ((float4*)out)[g] = make_float4(r.x + a.x + b.x, r.y + a.y + b.y,
                                  r.z + a.z + b.z, r.w + a.w + b.w);
}

// ---------- bf16 MFMA GEMM: double-buffered, BK=64 (one barrier per K-step) ----------
// LDS rows are 128 B: bank group = chunk only, so swizzle chunk ^= (row&7), both sides.
// EPI: 0 = bf16 out col-split C1/C2; 1 = softplus(acc+bias) bf16; 2 = f32 out + resid add;
//      5 = f32 partial store at C1 + blockIdx.z*split (coalesced, no atomics)
template <int EPI>
__global__ __launch_bounds__(256) void gemm_bt(
    const u16* __restrict__ A, const u16* __restrict__ Bw,
    void* __restrict__ C1, void* __restrict__ C2,
    const float* __restrict__ bias, const float* __restrict__ resid,
    int Kslice, int lda, int ldb, int ldc, int split, int nstore) {
  __shared__ alignas(16) u16 As[2][128 * 64];
  __shared__ alignas(16) u16 Bs[2][128 * 64];
  const int tid = threadIdx.x;
  const int lane = tid & 63, wid = tid >> 6;
  const int wr = wid >> 1, wcid = wid & 1;

  int bx, by;
  {
    const int gy = gridDim.y;
    const int flat = blockIdx.y * 32 + blockIdx.x;
    if ((gy & 3) == 0) {
      const int xcd = flat & 7, idx = flat >> 3;
      const int sy = gy >> 2;
      bx = (xcd & 1) * 16 + (idx & 15);
      by = (xcd >> 1) * sy + (idx >> 4);
    } else { bx = blockIdx.x; by = blockIdx.y; }
  }

  const long brow = (long)bx * 128, bcol = (long)by * 128;
  const int kt0 = blockIdx.z * Kslice;
  const int nt = Kslice >> 6;

  f32x4 acc[4][4] = {};

  const int srow = tid >> 3;                        // 0..31 (4 issues cover 128 rows)
  const int scol = ((tid & 7) ^ (srow & 7)) * 8;    // pre-swizzled global 16B-chunk
  const u16* Ag = A + (brow + srow) * (long)lda + scol;
  const u16* Bg = Bw + (bcol + srow) * (long)ldb + scol;
  const int fr = lane & 15;
  const int fq = lane >> 4;
  const int ck0 = ((fq) ^ (fr & 7)) * 8;            // swizzled read chunk, kslice 0
  const int ck1 = ((4 + fq) ^ (fr & 7)) * 8;        // kslice 1

  auto stage = [&](int buf, int kt) {
    u16* Asp = As[buf] + tid * 8;
    u16* Bsp = Bs[buf] + tid * 8;
#pragma unroll
    for (int kq = 0; kq < 4; ++kq) {
      load_lds16(Ag + kt + (long)(kq * 32) * lda, Asp + kq * 2048);
      load_lds16(Bg + kt + (long)(kq * 32) * ldb, Bsp + kq * 2048);
    }
  };

  stage(0, kt0);
  __syncthreads();

  int cur = 0;
  for (int t = 0; t < nt; ++t) {
    if (t + 1 < nt) stage(cur ^ 1, kt0 + (t + 1) * 64);   // overlaps with compute below
#pragma unroll
    for (int ks = 0; ks < 2; ++ks) {
      const int ck = ks ? ck1 : ck0;
      bf16x8 af[4], bfr[4];
#pragma unroll
      for (int i = 0; i < 4; ++i) {
        af[i]  = *(const bf16x8*)(As[cur] + (wr * 64 + i * 16 + fr) * 64 + ck);
        bfr[i] = *(const bf16x8*)(Bs[cur] + (wcid * 64 + i * 16 + fr) * 64 + ck);
      }
#pragma unroll
      for (int i = 0; i < 4; ++i)
#pragma unroll
        for (int j = 0; j < 4; ++j)
          acc[i][j] = __builtin_amdgcn_mfma_f32_16x16x32_bf16(af[i], bfr[j], acc[i][j], 0, 0, 0);
    }
    if (t + 1 < nt) __syncthreads();  // drains vmcnt -> next buf staged; guards LDS reuse
    cur ^= 1;
  }

#pragma unroll
  for (int i = 0; i < 4; ++i) {
#pragma unroll
    for (int j = 0; j < 4; ++j) {
      const long col = bcol + wcid * 64 + j * 16 + fr;
      if ((int)col < nstore) {
#pragma unroll
        for (int r = 0; r < 4; ++r) {
          const long row = brow + wr * 64 + i * 16 + fq * 4 + r;
          float v = acc[i][j][r];
          if (EPI == 1) {
            v += bias[col];
            v = fmaxf(v, 0.f) + log1pf(__expf(-fabsf(v)));  // softplus
          }
          if (EPI == 5) {
            ((float*)C1)[(size_t)blockIdx.z * split + row * ldc + col] = v;
          } else if (EPI == 2) {
            ((float*)C1)[row * ldc + col] = v + resid[row * ldc + col];
          } else if (EPI == 0 && (int)col < split) {
            ((u16*)C1)[row * ldc + col] = f2bf(v);
          } else if (EPI == 0) {
            ((u16*)C2)[row * ldc + (col - split)] = f2bf(v);
          } else if (EPI == 1) {
            ((u16*)C1)[row * ldc + col] = f2bf(v);
          }
        }
      }
    }
  }
}

// ---------- causal depthwise conv (K=4) + SiLU, 8e/thread ----------
__global__ __launch_bounds__(256) void conv_silu_kernel(
    const u16* __restrict__ u, const float* __restrict__ cw, const float* __restrict__ cb,
    u16* __restrict__ xc) {
  const int row = blockIdx.x;          // b*2048 + l
  const int l = row & 2047;
  const int t = threadIdx.x;
  const int e0 = t * 8;
  const size_t base = (size_t)row * 2048 + e0;
  bf16x8 xv[4];
#pragma unroll
  for (int k = 0; k < 4; ++k) {
    const int ls = l - 3 + k;
    if (ls >= 0) xv[k] = *(const bf16x8*)(u + base + (long)(k - 3) * 2048);
    else { bf16x8 z = {}; xv[k] = z; }
  }
  u16x8 o;
#pragma unroll
  for (int j = 0; j < 8; ++j) {
    const int e = e0 + j;
    const float4 w = ((const float4*)cw)[e];
    float acc = cb[e];
    acc = fmaf(w.x, (float)xv[0][j], acc);
    acc = fmaf(w.y, (float)xv[1][j], acc);
    acc = fmaf(w.z, (float)xv[2][j], acc);
    acc = fmaf(w.w, (float)xv[3][j], acc);
    const float s = acc / (1.f + __expf(-acc));  // silu
    o[j] = f2bf(s);
  }
  *(u16x8*)(xc + base) = o;
}

// ---------- selective scan, chunked: 64 chunks x 32 steps ----------
__global__ __launch_bounds__(256) void scan_p1(
    const u16* __restrict__ delta, const u16* __restrict__ xc, const u16* __restrict__ t96,
    const float* __restrict__ A_log, float* __restrict__ P, float* __restrict__ H) {
  const int tid = threadIdx.x;
  const int e = blockIdx.x * 256 + tid;
  const int c = blockIdx.y, b = blockIdx.z;
  __shared__ alignas(16) u16 Dsh[32 * 256];
  __shared__ alignas(16) u16 Xsh[32 * 256];
  __shared__ float Bsh[32][16];
  const size_t rowbase = ((size_t)(b * 2048 + c * 32)) * 2048 + blockIdx.x * 256;
#pragma unroll
  for (int k = 0; k < 4; ++k) {
    const int i = tid + k * 256;
    const size_t go = rowbase + (size_t)(i >> 5) * 2048 + (i & 31) * 8;
    load_lds16(delta + go, Dsh + i * 8);
    load_lds16(xc + go, Xsh + i * 8);
  }
  for (int i = tid; i < 512; i += 256) {
    const int l0 = i >> 4, n = i & 15;
    Bsh[l0][n] = bf2f(t96[(size_t)(b * 2048 + c * 32 + l0) * 96 + 64 + n]);
  }
  float kv[16], h[16];
#pragma unroll
  for (int n = 0; n < 16; ++n) {
    kv[n] = -__expf(A_log[(size_t)e * 16 + n]) * LOG2E;
    h[n] = 0.f;
  }
  __syncthreads();
  float sdt = 0.f;
  for (int l0 = 0; l0 < 32; ++l0) {
    const float dt = bf2f(Dsh[l0 * 256 + tid]);
    const float x  = bf2f(Xsh[l0 * 256 + tid]);
    const float dtx = dt * x;
    sdt += dt;
#pragma unroll
    for (int n = 0; n < 16; ++n) {
      const float ab = fexp2(kv[n] * dt);
      h[n] = fmaf(ab, h[n], dtx * Bsh[l0][n]);
    }
  }
  const size_t o0 = (((size_t)(b * 64 + c)) * 16) * 2048 + e;
#pragma unroll
  for (int n = 0; n < 16; ++n) {
    P[o0 + (size_t)n * 2048] = fexp2(kv[n] * sdt);
    H[o0 + (size_t)n * 2048] = h[n];
  }
}

__global__ __launch_bounds__(256) void scan_p2(float* __restrict__ P, float* __restrict__ H) {
  const int g = blockIdx.x * 256 + threadIdx.x;  // 65536 = B*E*N
  const int e = g & 2047;
  const int n = (g >> 11) & 15;
  const int b = g >> 15;
  const size_t base = (((size_t)(b * 64)) * 16 + n) * 2048 + e;
  float h = 0.f;
  for (int c = 0; c < 64; ++c) {
    const size_t a = base + (size_t)c * (16 * 2048);
    const float Pc = P[a], hl = H[a];
    H[a] = h;
    h = fmaf(Pc, h, hl);
  }
}

__global__ __launch_bounds__(256) void scan_p3(
    const u16* __restrict__ delta, const u16* __restrict__ xc, const u16* __restrict__ t96,
    const float* __restrict__ A_log, const float* __restrict__ Hin,
    const u16* __restrict__ skip, const float* __restrict__ W_D, u16* __restrict__ ybar) {
  const int tid = threadIdx.x;
  const int e = blockIdx.x * 256 + tid;
  const int c = blockIdx.y, b = blockIdx.z;
  __shared__ alignas(16) u16 Dsh[32 * 256];
  __shared__ alignas(16) u16 Xsh[32 * 256];
  __shared__ float Bsh[32][16], Csh[32][16];
  const size_t rowbase = ((size_t)(b * 2048 + c * 32)) * 2048 + blockIdx.x * 256;
#pragma unroll
  for (int k = 0; k < 4; ++k) {
    const int i = tid + k * 256;
    const size_t go = rowbase + (size_t)(i >> 5) * 2048 + (i & 31) * 8;
    load_lds16(delta + go, Dsh + i * 8);
    load_lds16(xc + go, Xsh + i * 8);
  }
  for (int i = tid; i < 512; i += 256) {
    const int l0 = i >> 4, n = i & 15;
    const size_t rowo = (size_t)(b * 2048 + c * 32 + l0) * 96;
    Bsh[l0][n] = bf2f(t96[rowo + 64 + n]);
    Csh[l0][n] = bf2f(t96[rowo + 80 + n]);
  }
  float kv[16], h[16];
  const size_t o0 = (((size_t)(b * 64 + c)) * 16) * 2048 + e;
#pragma unroll
  for (int n = 0; n < 16; ++n) {
    kv[n] = -__expf(A_log[(size_t)e * 16 + n]) * LOG2E;
    h[n] = Hin[o0 + (size_t)n * 2048];
  }
  const float wd = W_D[e];
  __syncthreads();
  const size_t base = ((size_t)(b * 2048 + c * 32)) * 2048 + e;
  for (int l0 = 0; l0 < 32; ++l0) {
    const float dt = bf2f(Dsh[l0 * 256 + tid]);
    const float x  = bf2f(Xsh[l0 * 256 + tid]);
    const float dtx = dt * x;
    float y = 0.f;
#pragma unroll
    for (int n = 0; n < 16; ++n) {
      const float ab = fexp2(kv[n] * dt);
      h[n] = fmaf(ab, h[n], dtx * Bsh[l0][n]);
      y = fmaf(h[n], Csh[l0][n], y);
    }
    y = fmaf(x, wd, y);
    const float s = bf2f(skip[base + (size_t)l0 * 2048]);
    y *= s / (1.f + __expf(-s));
    ybar[base + (size_t)l0 * 2048] = f2bf(y);
  }
}

// ---------- launch ----------
extern "C" void kernel_launch(void* const* d_in, const int* in_sizes, int n_in,
                              void* d_out, int out_size, void* d_ws, size_t ws_size,
                              hipStream_t stream) {
  const float* resid  = (const float*)d_in[0];
  const float* norm_w = (const float*)d_in[1];
  const float* skip_w = (const float*)d_in[2];
  const float* in_w   = (const float*)d_in[3];
  const float* conv_w = (const float*)d_in[4];
  const float* conv_b = (const float*)d_in[5];
  const float* wd1    = (const float*)d_in[6];
  const float* wd2    = (const float*)d_in[7];
  const float* wd2_b  = (const float*)d_in[8];
  const float* wb     = (const float*)d_in[9];
  const float* wc     = (const float*)d_in[10];
  const float* A_log  = (const float*)d_in[11];
  const float* W_D    = (const float*)d_in[12];
  const float* out_w  = (const float*)d_in[13];
  float* out = (float*)d_out;

  char* ws = (char*)d_ws;
  u16* w_in   = (u16*)(ws + 0);          // w_in|w_skip contiguous = fused 4096x1024 weight
  u16* w_skip = (u16*)(ws + 4194304);
  u16* w_out  = (u16*)(ws + 8388608);
  u16* w_wd2  = (u16*)(ws + 12582912);
  u16* w2cat  = (u16*)(ws + 12845056);   // 128 x 2048 (wd1,wb,wc,zeros)
  u16* xn     = (u16*)(ws + 13369344);   // 4096 x 1024
  u16* u      = (u16*)(ws + 21757952);   // 4096 x 2048
  u16* delta  = u;                       // alias: u dead after conv
  u16* skip   = (u16*)(ws + 38535168);   // 4096 x 2048
  float* outp = (float*)(ws + 21757952); // alias: 2 x (4096x1024) f32 out-proj partials
                                         // (delta+skip dead at out-proj; regions contiguous)
  u16* xc     = (u16*)(ws + 55312384);   // 4096 x 2048
  u16* t96    = (u16*)(ws + 72089600);   // 4096 x 96 bf16
  float* P    = (float*)(ws + 72876032); // (B,64,16,E)
  float* t96f = (float*)(ws + 72876032); // alias: 4 x (4096x96) f32 partials (dead before P)
  u16* ybar   = (u16*)(ws + 72876032);   // alias: P dead after phase 2
  float* H    = (float*)(ws + 89653248); // (B,64,16,E)

  CvtArgs ca{};
  ca.src[0] = in_w;   ca.dst[0] = w_in;              ca.cnt4[0] = 2097152 / 4;
  ca.src[1] = skip_w; ca.dst[1] = w_skip;            ca.cnt4[1] = 2097152 / 4;
  ca.src[2] = out_w;  ca.dst[2] = w_out;             ca.cnt4[2] = 2097152 / 4;
  ca.src[3] = wd2;    ca.dst[3] = w_wd2;             ca.cnt4[3] = 131072 / 4;
  ca.src[4] = wd1;    ca.dst[4] = w2cat;             ca.cnt4[4] = 131072 / 4;
  ca.src[5] = wb;     ca.dst[5] = w2cat + 64 * 2048; ca.cnt4[5] = 32768 / 4;
  ca.src[6] = wc;     ca.dst[6] = w2cat + 80 * 2048; ca.cnt4[6] = 32768 / 4;
  ca.src[7] = nullptr;ca.dst[7] = w2cat + 96 * 2048; ca.cnt4[7] = 65536 / 4;
  ca.total4 = (2097152 * 3 + 131072 * 2 + 32768 * 2 + 65536) / 4;

  // fused weight-convert + RMSNorm (one launch)
  prep_kernel<<<6144, 256, 0, stream>>>(ca, resid, norm_w, xn);

  // fused: [u | skip] = xn @ [in_w; skip_w]^T   (M=4096, N=4096, K=1024)
  gemm_bt<0><<<dim3(32, 32), 256, 0, stream>>>(xn, w_in, u, skip, nullptr, nullptr,
                                               1024, 1024, 1024, 2048, 2048, 4096);

  conv_silu_kernel<<<4096, 256, 0, stream>>>(u, conv_w, conv_b, xc);

  // t96 partials = xc @ [wd1;wb;wc]^T, split-K x4, coalesced f32 stores (no atomics)
  gemm_bt<5><<<dim3(32, 1, 4), 256, 0, stream>>>(xc, w2cat, t96f, nullptr, nullptr, nullptr,
                                                 512, 2048, 2048, 96, 4096 * 96, 96);
  reduce_t96_kernel<<<384, 256, 0, stream>>>(t96f, t96);

  // delta = softplus(dtr @ wd2^T + b)   (K=64 -> nt=1, single-buffer path)
  gemm_bt<1><<<dim3(32, 16), 256, 0, stream>>>(t96, w_wd2, delta, nullptr, wd2_b, nullptr,
                                               64, 96, 64, 2048, 1 << 30, 2048);

  scan_p1<<<dim3(8, 64, 2), 256, 0, stream>>>(delta, xc, t96, A_log, P, H);
  scan_p2<<<256, 256, 0, stream>>>(P, H);
  scan_p3<<<dim3(8, 64, 2), 256, 0, stream>>>(delta, xc, t96, A_log, H, skip, W_D, ybar);

  // out-proj: split-K x2 coalesced f32 partials (delta/skip regions now dead),
  // then fused reduce with resid add. No atomics (round-11 lesson).
  gemm_bt<5><<<dim3(32, 8, 2), 256, 0, stream>>>(ybar, w_out, outp, nullptr, nullptr, nullptr,
                                                 1024, 2048, 2048, 1024, 4096 * 1024, 1024);
  reduce_out_kernel<<<4096, 256, 0, stream>>>(outp, resid, out);
}